// Round 12
// baseline (118.189 us; speedup 1.0000x reference)
//
#include <hip/hip_runtime.h>

#define NPROP 8192
#define NT 1024
#define CAPV 4096   // LDS box capacity (64 KiB); V>CAPV falls back to global reads
typedef unsigned long long u64;

__device__ __forceinline__ int bucket_of(float s) {
    int b = (int)(s * 8192.0f);   // exact: *2^13 is an exponent shift
    return b < 0 ? 0 : (b > NPROP - 1 ? NPROP - 1 : b);
}

__device__ __forceinline__ bool iou_gt_thr(float4 a, float4 b) {
    float areaA = (a.z - a.x) * (a.w - a.y);
    float areaB = (b.z - b.x) * (b.w - b.y);
    float lx = fmaxf(a.x, b.x), ly = fmaxf(a.y, b.y);
    float rx = fminf(a.z, b.z), ry = fminf(a.w, b.w);
    float w = fmaxf(rx - lx, 0.0f), h = fmaxf(ry - ly, 0.0f);
    float inter = w * h;
    float uni = areaA + areaB - inter;
    float iou = inter / fmaxf(uni, 1e-6f);
    return iou > 0.3f;
}

// K1: LDS histogram + scan + scatter (1 block; allocator stays in LDS)
__global__ __launch_bounds__(NT)
void k_sort1(const float* __restrict__ scores, int* __restrict__ pref_ex,
             int* __restrict__ tmp_idx) {
    __shared__ int hist[NPROP];   // 32 KiB: counts -> allocator
    __shared__ int wsum[16], wexcl[16];
    const int tid = threadIdx.x, lane = tid & 63, wave = tid >> 6;
    #pragma unroll
    for (int u = 0; u < 8; u++) hist[tid * 8 + u] = 0;
    __syncthreads();
    const float4* s4 = reinterpret_cast<const float4*>(scores);
    float4 sa = s4[tid * 2], sb = s4[tid * 2 + 1];
    float ss[8] = {sa.x, sa.y, sa.z, sa.w, sb.x, sb.y, sb.z, sb.w};
    int bk[8];
    #pragma unroll
    for (int u = 0; u < 8; u++) { bk[u] = bucket_of(ss[u]); atomicAdd(&hist[bk[u]], 1); }
    __syncthreads();
    int h[8]; int tot = 0;
    #pragma unroll
    for (int u = 0; u < 8; u++) { h[u] = hist[tid * 8 + u]; tot += h[u]; }
    int incl = tot;
    #pragma unroll
    for (int off = 1; off < 64; off <<= 1) {
        int n = __shfl_up(incl, off, 64);
        if (lane >= off) incl += n;
    }
    if (lane == 63) wsum[wave] = incl;
    __syncthreads();
    if (tid == 0) {
        int acc = 0;
        #pragma unroll
        for (int w = 0; w < 16; w++) { int t = wsum[w]; wexcl[w] = acc; acc += t; }
    }
    __syncthreads();
    int run = wexcl[wave] + (incl - tot);
    int run2 = run;
    #pragma unroll
    for (int u = 0; u < 8; u++) { pref_ex[tid * 8 + u] = run; run += h[u]; }
    __syncthreads();   // all hist reads done before overwrite as allocator
    #pragma unroll
    for (int u = 0; u < 8; u++) { hist[tid * 8 + u] = run2; run2 += h[u]; }
    __syncthreads();
    #pragma unroll
    for (int u = 0; u < 8; u++) {
        int slot = atomicAdd(&hist[bk[u]], 1);
        tmp_idx[slot] = tid * 8 + u;
    }
}

// K2: exact stable rank via in-bucket counting + validity
__global__ void k_rank(const float* __restrict__ scores, const float* __restrict__ boxes,
                       const float* __restrict__ img,
                       const int* __restrict__ tmp_idx, const int* __restrict__ pref_ex,
                       float4* __restrict__ srt_box, float* __restrict__ srt_sv) {
    int p = blockIdx.x * blockDim.x + threadIdx.x;
    if (p >= NPROP) return;
    int i = tmp_idx[p];
    float s = scores[i];
    u64 key = ((u64)__float_as_uint(s) << 32) | (u64)(unsigned)(NPROP - 1 - i);
    int b = bucket_of(s);
    int lo = pref_ex[b];
    int hi = (b < NPROP - 1) ? pref_ex[b + 1] : NPROP;
    int cnt = 0;
    for (int q = lo; q < hi; q++) {
        int j = tmp_idx[q];
        u64 kj = ((u64)__float_as_uint(scores[j]) << 32) | (u64)(unsigned)(NPROP - 1 - j);
        cnt += (kj < key) ? 1 : 0;
    }
    int rank = NPROP - 1 - (lo + cnt);
    float4 bx = reinterpret_cast<const float4*>(boxes)[i];
    float ix1 = img[0], iy1 = img[1], ix2 = img[2], iy2 = img[3];
    float img_area = (ix2 - ix1) * (iy2 - iy1);
    float w = bx.z - bx.x, hh = bx.w - bx.y;
    float ratio = w / (hh + 1e-12f);
    bool vs = (ratio > 0.25f) && (ratio < 4.0f);
    float lx = fmaxf(ix1, bx.x), ly = fmaxf(iy1, bx.y);
    float rx = fminf(ix2, bx.z), ry = fminf(iy2, bx.w);
    float iw = fmaxf(rx - lx, 0.0f), ih = fmaxf(ry - ly, 0.0f);
    float iof = (iw * ih) / fmaxf(img_area, 1e-6f);
    bool vf = vs && (iof > 0.01f) && (s > 0.85f);
    srt_box[rank] = bx;
    srt_sv[rank] = __uint_as_float(__float_as_uint(s) | (vf ? 0x80000000u : 0u));
}

// K3: fused compact + on-the-fly-IoU blocked greedy resolve (boxes in LDS)
__global__ __launch_bounds__(NT)
void k_nms(const float4* __restrict__ srt_box, const float* __restrict__ srt_sv,
           float4* __restrict__ cbox, int* __restrict__ crank,
           u64* __restrict__ remG) {
    extern __shared__ char smem[];
    float4* boxsh = (float4*)smem;                       // 64 KiB
    u64* diag = (u64*)(smem + CAPV * 16);                // 512 B
    u64* rem  = (u64*)(smem + CAPV * 16 + 512);          // 1 KiB
    __shared__ int wsum[16], wexcl[16];
    __shared__ int vsh;

    const int tid = threadIdx.x, lane = tid & 63, wave = tid >> 6;

    // ---- compact valid subset into LDS (+ global write-through) ----
    bool vf[8]; int tot = 0; float4 bx[8];
    #pragma unroll
    for (int u = 0; u < 8; u++) {
        int p = tid * 8 + u;
        bx[u] = srt_box[p];
        vf[u] = (__float_as_uint(srt_sv[p]) >> 31) != 0;
        tot += vf[u] ? 1 : 0;
    }
    int incl = tot;
    #pragma unroll
    for (int off = 1; off < 64; off <<= 1) {
        int n = __shfl_up(incl, off, 64);
        if (lane >= off) incl += n;
    }
    if (lane == 63) wsum[wave] = incl;
    __syncthreads();
    if (tid == 0) {
        int acc = 0;
        #pragma unroll
        for (int w = 0; w < 16; w++) { int t = wsum[w]; wexcl[w] = acc; acc += t; }
        vsh = acc;
    }
    __syncthreads();
    const int vraw = vsh;
    const int V = vraw == 0 ? 1 : vraw;
    const int W = (V + 63) >> 6;
    int base = wexcl[wave] + (incl - tot);
    #pragma unroll
    for (int u = 0; u < 8; u++) {
        int p = tid * 8 + u;
        if (vf[u]) {
            crank[p] = base;
            if (base < CAPV) boxsh[base] = bx[u];
            cbox[base] = bx[u];
            base++;
        } else crank[p] = -1;
    }
    if (vraw == 0 && tid == 0) {
        crank[0] = 0; boxsh[0] = bx[0]; cbox[0] = bx[0];
    }
    for (int w = tid; w < NPROP / 64; w += NT) {
        int b0 = w * 64; u64 m;
        if (b0 >= V) m = ~0ull;
        else if (b0 + 64 <= V) m = 0ull;
        else m = (~0ull) << (V - b0);
        rem[w] = m;
    }
    __syncthreads();

    // ---- blocked greedy resolve, all IoU from LDS ----
    for (int b = 0; b < W; b++) {
        const int rb0 = b << 6;
        // Phase A: intra-block diag ballots (4 rows per wave)
        #pragma unroll
        for (int t = 0; t < 4; t++) {
            int i = (wave << 2) | t;
            int r = rb0 + i;
            float4 br;
            if (r < V) br = (r < CAPV) ? boxsh[r] : cbox[r];
            else       br = make_float4(0.f, 0.f, 0.f, 0.f);
            int col = rb0 + lane;
            bool ok = (r < V) && (col < V) && (lane > i);
            if (ok) {
                float4 bc = (col < CAPV) ? boxsh[col] : cbox[col];
                ok = iou_gt_thr(br, bc);
            }
            u64 bal = __ballot(ok);
            if (lane == 0) diag[i] = bal;
        }
        __syncthreads();
        // Phase B: kept-only scalar chain on wave 0
        if (tid < 64) {
            u64 d = diag[lane];
            int dlo = (int)(unsigned)(d & 0xffffffffull);
            int dhi = (int)(unsigned)(d >> 32);
            u64 r0 = rem[b];
            unsigned rl_ = (unsigned)__builtin_amdgcn_readfirstlane((int)(unsigned)(r0 & 0xffffffffull));
            unsigned rh_ = (unsigned)__builtin_amdgcn_readfirstlane((int)(unsigned)(r0 >> 32));
            u64 r = ((u64)rh_ << 32) | (u64)rl_;
            u64 avail = ~r;                 // candidates (pad bits pre-removed)
            while (avail) {
                int i = (int)__builtin_ctzll(avail);          // lowest candidate -> KEPT
                unsigned xl = (unsigned)__builtin_amdgcn_readlane(dlo, i);
                unsigned xh = (unsigned)__builtin_amdgcn_readlane(dhi, i);
                u64 di = ((u64)xh << 32) | (u64)xl;
                r |= di;
                u64 x = avail & ~di;
                avail = x & (x - 1);
            }
            if (lane == 0) rem[b] = r;
        }
        __syncthreads();
        // Phase C: kept rows of block b suppress later columns (uniform km walk)
        u64 keptm = ~rem[b];
        for (int j = rb0 + 64 + tid; j < V; j += NT) {
            int w2 = j >> 6;
            u64 rw = rem[w2];               // uniform per wave (same word)
            if (rw == ~0ull) continue;      // whole word already suppressed
            float4 bj = (j < CAPV) ? boxsh[j] : cbox[j];
            bool sup = false;
            u64 km = keptm;                 // uniform -> lockstep walk, no divergence
            while (km) {
                int i = (int)__builtin_ctzll(km);
                km &= km - 1;
                int rr = rb0 + i;
                float4 bi = (rr < CAPV) ? boxsh[rr] : cbox[rr];   // LDS broadcast
                sup = sup | iou_gt_thr(bi, bj);
            }
            u64 bal = __ballot(sup);
            if (lane == 0 && bal) rem[w2] |= bal;   // word owned by this wave
        }
        __syncthreads();
    }

    for (int w = tid; w < NPROP / 64; w += NT) remG[w] = rem[w];
}

// K4: final output [N,5]*keep + keep mask, vectorized float4 stores (4 CUs)
__global__ __launch_bounds__(256)
void k_out(const float4* __restrict__ srt_box, const float* __restrict__ srt_sv,
           const int* __restrict__ crank, const u64* __restrict__ remG,
           float* __restrict__ out) {
    int tid = blockIdx.x * 256 + threadIdx.x;   // 0..1023, 8 positions each
    float ob[40]; float om[8];
    #pragma unroll
    for (int u = 0; u < 8; u++) {
        int p = tid * 8 + u;
        float4 b = srt_box[p];
        unsigned svb = __float_as_uint(srt_sv[p]);
        float s = __uint_as_float(svb & 0x7fffffffu);
        int k = crank[p];
        bool keep = (k >= 0) && !((remG[k >> 6] >> (k & 63)) & 1ull);
        float m = keep ? 1.0f : 0.0f;
        ob[u * 5 + 0] = b.x * m;
        ob[u * 5 + 1] = b.y * m;
        ob[u * 5 + 2] = b.z * m;
        ob[u * 5 + 3] = b.w * m;
        ob[u * 5 + 4] = s * m;
        om[u] = m;
    }
    float4* o4 = reinterpret_cast<float4*>(out) + tid * 10;
    #pragma unroll
    for (int q = 0; q < 10; q++)
        o4[q] = make_float4(ob[q * 4 + 0], ob[q * 4 + 1], ob[q * 4 + 2], ob[q * 4 + 3]);
    float4* m4 = reinterpret_cast<float4*>(out + NPROP * 5) + tid * 2;
    m4[0] = make_float4(om[0], om[1], om[2], om[3]);
    m4[1] = make_float4(om[4], om[5], om[6], om[7]);
}

extern "C" void kernel_launch(void* const* d_in, const int* in_sizes, int n_in,
                              void* d_out, int out_size, void* d_ws, size_t ws_size,
                              hipStream_t stream) {
    const float* boxes  = (const float*)d_in[0];
    const float* scores = (const float*)d_in[1];
    const float* img    = (const float*)d_in[2];
    char* ws = (char*)d_ws;
    int*    pref_ex  = (int*)(ws + 0);         // 32 KiB
    int*    tmp_idx  = (int*)(ws + 32768);     // 32 KiB
    float*  srt_sv   = (float*)(ws + 65536);   // 32 KiB
    float4* srt_box  = (float4*)(ws + 98304);  // 128 KiB
    float4* cbox     = (float4*)(ws + 229376); // 128 KiB
    int*    crank    = (int*)(ws + 360448);    // 32 KiB
    u64*    remG     = (u64*)(ws + 393216);    // 1 KiB
    float* out = (float*)d_out;

    k_sort1<<<1, NT, 0, stream>>>(scores, pref_ex, tmp_idx);
    k_rank<<<32, 256, 0, stream>>>(scores, boxes, img, tmp_idx, pref_ex,
                                   srt_box, srt_sv);
    k_nms<<<1, NT, CAPV * 16 + 1536, stream>>>(srt_box, srt_sv, cbox, crank, remG);
    k_out<<<4, 256, 0, stream>>>(srt_box, srt_sv, crank, remG, out);
}

// Round 13
// 115.219 us; speedup vs baseline: 1.0258x; 1.0258x over previous
//
#include <hip/hip_runtime.h>

#define NPROP 8192
#define NT 1024
#define CAPV 4096   // LDS box capacity (64 KiB); V>CAPV falls back to global reads
typedef unsigned long long u64;

__device__ __forceinline__ int bucket_of(float s) {
    int b = (int)(s * 8192.0f);   // exact: *2^13 is an exponent shift
    return b < 0 ? 0 : (b > NPROP - 1 ? NPROP - 1 : b);
}

__device__ __forceinline__ bool iou_gt_thr(float4 a, float4 b) {
    float areaA = (a.z - a.x) * (a.w - a.y);
    float areaB = (b.z - b.x) * (b.w - b.y);
    float lx = fmaxf(a.x, b.x), ly = fmaxf(a.y, b.y);
    float rx = fminf(a.z, b.z), ry = fminf(a.w, b.w);
    float w = fmaxf(rx - lx, 0.0f), h = fmaxf(ry - ly, 0.0f);
    float inter = w * h;
    float uni = areaA + areaB - inter;
    float iou = inter / fmaxf(uni, 1e-6f);
    return iou > 0.3f;
}

// K1: LDS histogram + scan + scatter (1 block; allocator stays in LDS)
__global__ __launch_bounds__(NT)
void k_sort1(const float* __restrict__ scores, int* __restrict__ pref_ex,
             int* __restrict__ tmp_idx) {
    __shared__ int hist[NPROP];   // 32 KiB: counts -> allocator
    __shared__ int wsum[16], wexcl[16];
    const int tid = threadIdx.x, lane = tid & 63, wave = tid >> 6;
    #pragma unroll
    for (int u = 0; u < 8; u++) hist[tid * 8 + u] = 0;
    __syncthreads();
    const float4* s4 = reinterpret_cast<const float4*>(scores);
    float4 sa = s4[tid * 2], sb = s4[tid * 2 + 1];
    float ss[8] = {sa.x, sa.y, sa.z, sa.w, sb.x, sb.y, sb.z, sb.w};
    int bk[8];
    #pragma unroll
    for (int u = 0; u < 8; u++) { bk[u] = bucket_of(ss[u]); atomicAdd(&hist[bk[u]], 1); }
    __syncthreads();
    int h[8]; int tot = 0;
    #pragma unroll
    for (int u = 0; u < 8; u++) { h[u] = hist[tid * 8 + u]; tot += h[u]; }
    int incl = tot;
    #pragma unroll
    for (int off = 1; off < 64; off <<= 1) {
        int n = __shfl_up(incl, off, 64);
        if (lane >= off) incl += n;
    }
    if (lane == 63) wsum[wave] = incl;
    __syncthreads();
    if (tid == 0) {
        int acc = 0;
        #pragma unroll
        for (int w = 0; w < 16; w++) { int t = wsum[w]; wexcl[w] = acc; acc += t; }
    }
    __syncthreads();
    int run = wexcl[wave] + (incl - tot);
    int run2 = run;
    #pragma unroll
    for (int u = 0; u < 8; u++) { pref_ex[tid * 8 + u] = run; run += h[u]; }
    __syncthreads();   // all hist reads done before overwrite as allocator
    #pragma unroll
    for (int u = 0; u < 8; u++) { hist[tid * 8 + u] = run2; run2 += h[u]; }
    __syncthreads();
    #pragma unroll
    for (int u = 0; u < 8; u++) {
        int slot = atomicAdd(&hist[bk[u]], 1);
        tmp_idx[slot] = tid * 8 + u;
    }
}

// K2: exact stable rank via in-bucket counting + validity
__global__ void k_rank(const float* __restrict__ scores, const float* __restrict__ boxes,
                       const float* __restrict__ img,
                       const int* __restrict__ tmp_idx, const int* __restrict__ pref_ex,
                       float4* __restrict__ srt_box, float* __restrict__ srt_sv) {
    int p = blockIdx.x * blockDim.x + threadIdx.x;
    if (p >= NPROP) return;
    int i = tmp_idx[p];
    float s = scores[i];
    u64 key = ((u64)__float_as_uint(s) << 32) | (u64)(unsigned)(NPROP - 1 - i);
    int b = bucket_of(s);
    int lo = pref_ex[b];
    int hi = (b < NPROP - 1) ? pref_ex[b + 1] : NPROP;
    int cnt = 0;
    for (int q = lo; q < hi; q++) {
        int j = tmp_idx[q];
        u64 kj = ((u64)__float_as_uint(scores[j]) << 32) | (u64)(unsigned)(NPROP - 1 - j);
        cnt += (kj < key) ? 1 : 0;
    }
    int rank = NPROP - 1 - (lo + cnt);
    float4 bx = reinterpret_cast<const float4*>(boxes)[i];
    float ix1 = img[0], iy1 = img[1], ix2 = img[2], iy2 = img[3];
    float img_area = (ix2 - ix1) * (iy2 - iy1);
    float w = bx.z - bx.x, hh = bx.w - bx.y;
    float ratio = w / (hh + 1e-12f);
    bool vs = (ratio > 0.25f) && (ratio < 4.0f);
    float lx = fmaxf(ix1, bx.x), ly = fmaxf(iy1, bx.y);
    float rx = fminf(ix2, bx.z), ry = fminf(iy2, bx.w);
    float iw = fmaxf(rx - lx, 0.0f), ih = fmaxf(ry - ly, 0.0f);
    float iof = (iw * ih) / fmaxf(img_area, 1e-6f);
    bool vf = vs && (iof > 0.01f) && (s > 0.85f);
    srt_box[rank] = bx;
    srt_sv[rank] = __uint_as_float(__float_as_uint(s) | (vf ? 0x80000000u : 0u));
}

// K3: fused compact + blocked greedy NMS (register columns + batched klist)
__global__ __launch_bounds__(NT)
void k_nms(const float4* __restrict__ srt_box, const float* __restrict__ srt_sv,
           float4* __restrict__ cbox, int* __restrict__ crank,
           u64* __restrict__ remG) {
    extern __shared__ char smem[];
    float4* boxsh = (float4*)smem;                       // 64 KiB
    float4* klist = (float4*)(smem + CAPV * 16);         // 1 KiB (64 boxes)
    u64* diag = (u64*)(smem + CAPV * 16 + 1024);         // 512 B
    u64* rem  = (u64*)(smem + CAPV * 16 + 1536);         // 1 KiB
    __shared__ int wsum[16], wexcl[16];
    __shared__ int vsh, nksh;

    const int tid = threadIdx.x, lane = tid & 63, wave = tid >> 6;

    // ---- compact valid subset into LDS (+ global write-through) ----
    bool vf[8]; int tot = 0; float4 bx[8];
    #pragma unroll
    for (int u = 0; u < 8; u++) {
        int p = tid * 8 + u;
        bx[u] = srt_box[p];
        vf[u] = (__float_as_uint(srt_sv[p]) >> 31) != 0;
        tot += vf[u] ? 1 : 0;
    }
    int incl = tot;
    #pragma unroll
    for (int off = 1; off < 64; off <<= 1) {
        int n = __shfl_up(incl, off, 64);
        if (lane >= off) incl += n;
    }
    if (lane == 63) wsum[wave] = incl;
    __syncthreads();
    if (tid == 0) {
        int acc = 0;
        #pragma unroll
        for (int w = 0; w < 16; w++) { int t = wsum[w]; wexcl[w] = acc; acc += t; }
        vsh = acc;
    }
    __syncthreads();
    const int vraw = vsh;
    const int V = vraw == 0 ? 1 : vraw;
    const int W = (V + 63) >> 6;
    int base = wexcl[wave] + (incl - tot);
    #pragma unroll
    for (int u = 0; u < 8; u++) {
        int p = tid * 8 + u;
        if (vf[u]) {
            crank[p] = base;
            if (base < CAPV) boxsh[base] = bx[u];
            cbox[base] = bx[u];
            base++;
        } else crank[p] = -1;
    }
    if (vraw == 0 && tid == 0) {
        crank[0] = 0; boxsh[0] = bx[0]; cbox[0] = bx[0];
    }
    for (int w = tid; w < NPROP / 64; w += NT) {
        int b0 = w * 64; u64 m;
        if (b0 >= V) m = ~0ull;
        else if (b0 + 64 <= V) m = 0ull;
        else m = (~0ull) << (V - b0);
        rem[w] = m;
    }
    __syncthreads();

    // ---- register-resident columns: thread owns j = c*NT + tid ----
    float4 colreg[8]; unsigned supm = 0;
    #pragma unroll
    for (int c = 0; c < 8; c++) {
        int j = c * NT + tid;
        if (j < V) colreg[c] = (j < CAPV) ? boxsh[j] : cbox[j];
        else { colreg[c] = make_float4(0.f, 0.f, 0.f, 0.f); supm |= 1u << c; }
    }

    // ---- blocked greedy resolve ----
    for (int b = 0; b < W; b++) {
        const int rb0 = b << 6;
        // Phase A: intra-block diag ballots (4 rows/wave, batched row reads)
        {
            int colj = rb0 + lane;
            bool colv = colj < V;
            float4 colb = make_float4(0.f, 0.f, 0.f, 0.f);
            if (colv) colb = (colj < CAPV) ? boxsh[colj] : cbox[colj];
            float4 br4[4];
            #pragma unroll
            for (int t = 0; t < 4; t++) {
                int r_ = rb0 + (wave << 2) + t;
                if (r_ < V) br4[t] = (r_ < CAPV) ? boxsh[r_] : cbox[r_];
            }
            #pragma unroll
            for (int t = 0; t < 4; t++) {
                int i = (wave << 2) | t;
                bool ok = colv && ((rb0 + i) < V) && (lane > i) &&
                          iou_gt_thr(br4[t], colb);
                u64 bal = __ballot(ok);
                if (lane == 0) diag[i] = bal;
            }
        }
        __syncthreads();
        // Phase B: kept-only scalar chain on wave 0 + compact klist build
        if (tid < 64) {
            u64 d = diag[lane];
            int dlo = (int)(unsigned)(d & 0xffffffffull);
            int dhi = (int)(unsigned)(d >> 32);
            u64 r0 = rem[b];
            unsigned rl_ = (unsigned)__builtin_amdgcn_readfirstlane((int)(unsigned)(r0 & 0xffffffffull));
            unsigned rh_ = (unsigned)__builtin_amdgcn_readfirstlane((int)(unsigned)(r0 >> 32));
            u64 r = ((u64)rh_ << 32) | (u64)rl_;
            u64 avail = ~r;                 // candidates (pad bits pre-removed)
            while (avail) {
                int i = (int)__builtin_ctzll(avail);          // lowest candidate -> KEPT
                unsigned xl = (unsigned)__builtin_amdgcn_readlane(dlo, i);
                unsigned xh = (unsigned)__builtin_amdgcn_readlane(dhi, i);
                u64 di = ((u64)xh << 32) | (u64)xl;
                r |= di;
                u64 x = avail & ~di;
                avail = x & (x - 1);
            }
            u64 keptb = ~r;                 // kept rows of this block
            if (lane == 0) { rem[b] = r; nksh = (int)__popcll(keptb); }
            if ((keptb >> lane) & 1ull) {
                int pos = (int)__popcll(keptb & ((1ull << lane) - 1ull));
                int row = rb0 + lane;
                klist[pos] = (row < CAPV) ? boxsh[row] : cbox[row];
            }
        }
        __syncthreads();
        // Phase C: each thread tests its own register columns vs klist (batched)
        const int nk = nksh;
        #pragma unroll
        for (int c = 0; c < 8; c++) {
            int cbase = c * NT;
            if (cbase >= V) break;
            if (cbase + NT <= rb0 + 64) continue;   // whole range before cols
            int j = cbase + tid;
            bool active = (j >= rb0 + 64) && !((supm >> c) & 1u);
            if (active) {
                float4 bj = colreg[c];
                bool s = false;
                int kk = 0;
                for (; kk + 4 <= nk && !s; kk += 4) {
                    float4 a0 = klist[kk + 0], a1 = klist[kk + 1];
                    float4 a2 = klist[kk + 2], a3 = klist[kk + 3];
                    s = iou_gt_thr(a0, bj) | iou_gt_thr(a1, bj) |
                        iou_gt_thr(a2, bj) | iou_gt_thr(a3, bj);
                }
                for (; kk < nk && !s; kk++) s = iou_gt_thr(klist[kk], bj);
                if (s) supm |= 1u << c;
            }
            u64 bal = __ballot((supm >> c) & 1u);
            int w2 = (c << 4) + wave;        // word owned by exactly this wave
            if (lane == 0 && bal) rem[w2] |= bal;
        }
        __syncthreads();
    }

    for (int w = tid; w < NPROP / 64; w += NT) remG[w] = rem[w];
}

// K4: final output [N,5]*keep + keep mask, vectorized float4 stores (4 CUs)
__global__ __launch_bounds__(256)
void k_out(const float4* __restrict__ srt_box, const float* __restrict__ srt_sv,
           const int* __restrict__ crank, const u64* __restrict__ remG,
           float* __restrict__ out) {
    int tid = blockIdx.x * 256 + threadIdx.x;   // 0..1023, 8 positions each
    float ob[40]; float om[8];
    #pragma unroll
    for (int u = 0; u < 8; u++) {
        int p = tid * 8 + u;
        float4 b = srt_box[p];
        unsigned svb = __float_as_uint(srt_sv[p]);
        float s = __uint_as_float(svb & 0x7fffffffu);
        int k = crank[p];
        bool keep = (k >= 0) && !((remG[k >> 6] >> (k & 63)) & 1ull);
        float m = keep ? 1.0f : 0.0f;
        ob[u * 5 + 0] = b.x * m;
        ob[u * 5 + 1] = b.y * m;
        ob[u * 5 + 2] = b.z * m;
        ob[u * 5 + 3] = b.w * m;
        ob[u * 5 + 4] = s * m;
        om[u] = m;
    }
    float4* o4 = reinterpret_cast<float4*>(out) + tid * 10;
    #pragma unroll
    for (int q = 0; q < 10; q++)
        o4[q] = make_float4(ob[q * 4 + 0], ob[q * 4 + 1], ob[q * 4 + 2], ob[q * 4 + 3]);
    float4* m4 = reinterpret_cast<float4*>(out + NPROP * 5) + tid * 2;
    m4[0] = make_float4(om[0], om[1], om[2], om[3]);
    m4[1] = make_float4(om[4], om[5], om[6], om[7]);
}

extern "C" void kernel_launch(void* const* d_in, const int* in_sizes, int n_in,
                              void* d_out, int out_size, void* d_ws, size_t ws_size,
                              hipStream_t stream) {
    const float* boxes  = (const float*)d_in[0];
    const float* scores = (const float*)d_in[1];
    const float* img    = (const float*)d_in[2];
    char* ws = (char*)d_ws;
    int*    pref_ex  = (int*)(ws + 0);         // 32 KiB
    int*    tmp_idx  = (int*)(ws + 32768);     // 32 KiB
    float*  srt_sv   = (float*)(ws + 65536);   // 32 KiB
    float4* srt_box  = (float4*)(ws + 98304);  // 128 KiB
    float4* cbox     = (float4*)(ws + 229376); // 128 KiB
    int*    crank    = (int*)(ws + 360448);    // 32 KiB
    u64*    remG     = (u64*)(ws + 393216);    // 1 KiB
    float* out = (float*)d_out;

    k_sort1<<<1, NT, 0, stream>>>(scores, pref_ex, tmp_idx);
    k_rank<<<32, 256, 0, stream>>>(scores, boxes, img, tmp_idx, pref_ex,
                                   srt_box, srt_sv);
    k_nms<<<1, NT, CAPV * 16 + 2560, stream>>>(srt_box, srt_sv, cbox, crank, remG);
    k_out<<<4, 256, 0, stream>>>(srt_box, srt_sv, crank, remG, out);
}

// Round 14
// 59.758 us; speedup vs baseline: 1.9778x; 1.9281x over previous
//
#include <hip/hip_runtime.h>

#define NPROP 8192
#define NT 1024
typedef unsigned long long u64;

__device__ __forceinline__ int bucket_of(float s) {
    int b = (int)(s * 8192.0f);   // exact: *2^13 is an exponent shift
    return b < 0 ? 0 : (b > NPROP - 1 ? NPROP - 1 : b);
}

__device__ __forceinline__ bool iou_gt_thr(float4 a, float4 b) {
    float areaA = (a.z - a.x) * (a.w - a.y);
    float areaB = (b.z - b.x) * (b.w - b.y);
    float lx = fmaxf(a.x, b.x), ly = fmaxf(a.y, b.y);
    float rx = fminf(a.z, b.z), ry = fminf(a.w, b.w);
    float w = fmaxf(rx - lx, 0.0f), h = fmaxf(ry - ly, 0.0f);
    float inter = w * h;
    float uni = areaA + areaB - inter;
    float iou = inter / fmaxf(uni, 1e-6f);
    return iou > 0.3f;
}

// K1: LDS histogram + scan + scatter (1 block; allocator stays in LDS)
__global__ __launch_bounds__(NT)
void k_sort1(const float* __restrict__ scores, int* __restrict__ pref_ex,
             int* __restrict__ tmp_idx) {
    __shared__ int hist[NPROP];   // 32 KiB: counts -> allocator
    __shared__ int wsum[16], wexcl[16];
    const int tid = threadIdx.x, lane = tid & 63, wave = tid >> 6;
    #pragma unroll
    for (int u = 0; u < 8; u++) hist[tid * 8 + u] = 0;
    __syncthreads();
    const float4* s4 = reinterpret_cast<const float4*>(scores);
    float4 sa = s4[tid * 2], sb = s4[tid * 2 + 1];
    float ss[8] = {sa.x, sa.y, sa.z, sa.w, sb.x, sb.y, sb.z, sb.w};
    int bk[8];
    #pragma unroll
    for (int u = 0; u < 8; u++) { bk[u] = bucket_of(ss[u]); atomicAdd(&hist[bk[u]], 1); }
    __syncthreads();
    int h[8]; int tot = 0;
    #pragma unroll
    for (int u = 0; u < 8; u++) { h[u] = hist[tid * 8 + u]; tot += h[u]; }
    int incl = tot;
    #pragma unroll
    for (int off = 1; off < 64; off <<= 1) {
        int n = __shfl_up(incl, off, 64);
        if (lane >= off) incl += n;
    }
    if (lane == 63) wsum[wave] = incl;
    __syncthreads();
    if (tid == 0) {
        int acc = 0;
        #pragma unroll
        for (int w = 0; w < 16; w++) { int t = wsum[w]; wexcl[w] = acc; acc += t; }
    }
    __syncthreads();
    int run = wexcl[wave] + (incl - tot);
    int run2 = run;
    #pragma unroll
    for (int u = 0; u < 8; u++) { pref_ex[tid * 8 + u] = run; run += h[u]; }
    __syncthreads();   // all hist reads done before overwrite as allocator
    #pragma unroll
    for (int u = 0; u < 8; u++) { hist[tid * 8 + u] = run2; run2 += h[u]; }
    __syncthreads();
    #pragma unroll
    for (int u = 0; u < 8; u++) {
        int slot = atomicAdd(&hist[bk[u]], 1);
        tmp_idx[slot] = tid * 8 + u;
    }
}

// K2: exact stable rank via in-bucket counting + validity
__global__ void k_rank(const float* __restrict__ scores, const float* __restrict__ boxes,
                       const float* __restrict__ img,
                       const int* __restrict__ tmp_idx, const int* __restrict__ pref_ex,
                       float4* __restrict__ srt_box, float* __restrict__ srt_sv) {
    int p = blockIdx.x * blockDim.x + threadIdx.x;
    if (p >= NPROP) return;
    int i = tmp_idx[p];
    float s = scores[i];
    u64 key = ((u64)__float_as_uint(s) << 32) | (u64)(unsigned)(NPROP - 1 - i);
    int b = bucket_of(s);
    int lo = pref_ex[b];
    int hi = (b < NPROP - 1) ? pref_ex[b + 1] : NPROP;
    int cnt = 0;
    for (int q = lo; q < hi; q++) {
        int j = tmp_idx[q];
        u64 kj = ((u64)__float_as_uint(scores[j]) << 32) | (u64)(unsigned)(NPROP - 1 - j);
        cnt += (kj < key) ? 1 : 0;
    }
    int rank = NPROP - 1 - (lo + cnt);
    float4 bx = reinterpret_cast<const float4*>(boxes)[i];
    float ix1 = img[0], iy1 = img[1], ix2 = img[2], iy2 = img[3];
    float img_area = (ix2 - ix1) * (iy2 - iy1);
    float w = bx.z - bx.x, hh = bx.w - bx.y;
    float ratio = w / (hh + 1e-12f);
    bool vs = (ratio > 0.25f) && (ratio < 4.0f);
    float lx = fmaxf(ix1, bx.x), ly = fmaxf(iy1, bx.y);
    float rx = fminf(ix2, bx.z), ry = fminf(iy2, bx.w);
    float iw = fmaxf(rx - lx, 0.0f), ih = fmaxf(ry - ly, 0.0f);
    float iof = (iw * ih) / fmaxf(img_area, 1e-6f);
    bool vf = vs && (iof > 0.01f) && (s > 0.85f);
    srt_box[rank] = bx;
    srt_sv[rank] = __uint_as_float(__float_as_uint(s) | (vf ? 0x80000000u : 0u));
}

// K3: compact valid subset + V/W meta
__global__ __launch_bounds__(NT)
void k_compact(const float4* __restrict__ srt_box, const float* __restrict__ srt_sv,
               float4* __restrict__ cbox, int* __restrict__ crank,
               int* __restrict__ meta) {
    __shared__ int wsum[16], wexcl[16];
    const int tid = threadIdx.x, lane = tid & 63, wave = tid >> 6;
    bool vf[8]; int tot = 0;
    float4 bx[8];
    #pragma unroll
    for (int u = 0; u < 8; u++) {
        int p = tid * 8 + u;
        bx[u] = srt_box[p];
        vf[u] = (__float_as_uint(srt_sv[p]) >> 31) != 0;
        tot += vf[u] ? 1 : 0;
    }
    int incl = tot;
    #pragma unroll
    for (int off = 1; off < 64; off <<= 1) {
        int n = __shfl_up(incl, off, 64);
        if (lane >= off) incl += n;
    }
    if (lane == 63) wsum[wave] = incl;
    __syncthreads();
    if (tid == 0) {
        int acc = 0;
        #pragma unroll
        for (int w = 0; w < 16; w++) { int t = wsum[w]; wexcl[w] = acc; acc += t; }
        int V = acc == 0 ? 1 : acc;
        meta[0] = V;
        meta[1] = (V + 63) >> 6;
        meta[2] = acc;              // raw count (0 => fallback)
    }
    __syncthreads();
    int base = wexcl[wave] + (incl - tot);
    #pragma unroll
    for (int u = 0; u < 8; u++) {
        int p = tid * 8 + u;
        if (vf[u]) { crank[p] = base; cbox[base] = bx[u]; base++; }
        else crank[p] = -1;
    }
    if (meta[2] == 0 && tid == 0) { crank[0] = 0; cbox[0] = srt_box[0]; }
}

// K4: suppression mask matrix — wave per row, lane per column
__global__ __launch_bounds__(256)
void k_mask(const float4* __restrict__ cbox, const int* __restrict__ meta,
            u64* __restrict__ mask) {
    const int V = meta[0], W = meta[1];
    const int lane = threadIdx.x & 63;
    int gw = blockIdx.x * 4 + (threadIdx.x >> 6);
    for (int r = gw; r < V; r += 1024) {
        float4 br = cbox[r];
        for (int w = (r >> 6); w < W; w++) {
            int col = w * 64 + lane;
            bool ok = (col < V) && (col > r) && iou_gt_thr(br, cbox[col]);
            u64 bal = __ballot(ok);
            if (lane == 0) mask[(u64)r * W + w] = bal;
        }
    }
}

// K5: PULL-based greedy resolve — no forward apply, one gather round per block
__global__ __launch_bounds__(NT)
void k_resolve(const u64* __restrict__ mask, const int* __restrict__ meta,
               u64* __restrict__ remG) {
    __shared__ u64 rem[NPROP / 64];   // 1 KiB
    __shared__ u64 diag[64];          // 512 B
    __shared__ u64 pullw[2];
    __shared__ int klidx[NPROP];      // 32 KiB kept-row indices
    __shared__ int Ksh;
    const int V = meta[0], W = meta[1];
    const int tid = threadIdx.x, lane = tid & 63, wave = tid >> 6;

    for (int w = tid; w < NPROP / 64; w += NT) {
        int b0 = w * 64; u64 m;
        if (b0 >= V) m = ~0ull;
        else if (b0 + 64 <= V) m = 0ull;
        else m = (~0ull) << (V - b0);
        rem[w] = m;
    }
    if (tid == 0) { Ksh = 0; pullw[0] = 0; pullw[1] = 0; }
    __syncthreads();

    for (int b = 0; b < W; b++) {
        const int rb0 = b << 6;
        const int K = Ksh;
        // gather round: pull words of all kept rows + this block's diag words
        u64 myor = 0;
        for (int t = tid; t < K; t += NT)
            myor |= mask[(u64)klidx[t] * W + b];
        if (wave == 15) {
            int r = rb0 + lane;
            diag[lane] = (r < V) ? mask[(u64)r * W + b] : 0ull;
        }
        #pragma unroll
        for (int off = 1; off < 64; off <<= 1)
            myor |= __shfl_xor(myor, off, 64);
        if (lane == 0 && myor)
            atomicOr((unsigned long long*)&pullw[b & 1], myor);
        __syncthreads();
        // chain on wave 0; thread 64 zeroes the other pull buffer for b+1
        if (tid == 64) pullw[(b & 1) ^ 1] = 0;
        if (tid < 64) {
            u64 d = diag[lane];
            int dlo = (int)(unsigned)(d & 0xffffffffull);
            int dhi = (int)(unsigned)(d >> 32);
            u64 r0 = rem[b] | pullw[b & 1];
            unsigned rl_ = (unsigned)__builtin_amdgcn_readfirstlane((int)(unsigned)(r0 & 0xffffffffull));
            unsigned rh_ = (unsigned)__builtin_amdgcn_readfirstlane((int)(unsigned)(r0 >> 32));
            u64 r = ((u64)rh_ << 32) | (u64)rl_;
            u64 avail = ~r;                 // candidates (pad bits pre-removed)
            while (avail) {
                int i = (int)__builtin_ctzll(avail);          // lowest candidate -> KEPT
                unsigned xl = (unsigned)__builtin_amdgcn_readlane(dlo, i);
                unsigned xh = (unsigned)__builtin_amdgcn_readlane(dhi, i);
                u64 di = ((u64)xh << 32) | (u64)xl;
                r |= di;
                u64 x = avail & ~di;
                avail = x & (x - 1);
            }
            u64 keptb = ~r;                 // kept rows of this block (pad bits 0)
            if (lane == 0) { rem[b] = r; Ksh = K + (int)__popcll(keptb); }
            if ((keptb >> lane) & 1ull) {
                int pos = (int)__popcll(keptb & ((1ull << lane) - 1ull));
                klidx[K + pos] = rb0 + lane;
            }
        }
        __syncthreads();
    }

    for (int w = tid; w < NPROP / 64; w += NT) remG[w] = rem[w];
}

// K6: final output [N,5]*keep + keep mask, vectorized float4 stores (4 CUs)
__global__ __launch_bounds__(256)
void k_out(const float4* __restrict__ srt_box, const float* __restrict__ srt_sv,
           const int* __restrict__ crank, const u64* __restrict__ remG,
           float* __restrict__ out) {
    int tid = blockIdx.x * 256 + threadIdx.x;   // 0..1023, 8 positions each
    float ob[40]; float om[8];
    #pragma unroll
    for (int u = 0; u < 8; u++) {
        int p = tid * 8 + u;
        float4 b = srt_box[p];
        unsigned svb = __float_as_uint(srt_sv[p]);
        float s = __uint_as_float(svb & 0x7fffffffu);
        int k = crank[p];
        bool keep = (k >= 0) && !((remG[k >> 6] >> (k & 63)) & 1ull);
        float m = keep ? 1.0f : 0.0f;
        ob[u * 5 + 0] = b.x * m;
        ob[u * 5 + 1] = b.y * m;
        ob[u * 5 + 2] = b.z * m;
        ob[u * 5 + 3] = b.w * m;
        ob[u * 5 + 4] = s * m;
        om[u] = m;
    }
    float4* o4 = reinterpret_cast<float4*>(out) + tid * 10;
    #pragma unroll
    for (int q = 0; q < 10; q++)
        o4[q] = make_float4(ob[q * 4 + 0], ob[q * 4 + 1], ob[q * 4 + 2], ob[q * 4 + 3]);
    float4* m4 = reinterpret_cast<float4*>(out + NPROP * 5) + tid * 2;
    m4[0] = make_float4(om[0], om[1], om[2], om[3]);
    m4[1] = make_float4(om[4], om[5], om[6], om[7]);
}

extern "C" void kernel_launch(void* const* d_in, const int* in_sizes, int n_in,
                              void* d_out, int out_size, void* d_ws, size_t ws_size,
                              hipStream_t stream) {
    const float* boxes  = (const float*)d_in[0];
    const float* scores = (const float*)d_in[1];
    const float* img    = (const float*)d_in[2];
    char* ws = (char*)d_ws;
    int*    pref_ex  = (int*)(ws + 0);         // 32 KiB
    int*    tmp_idx  = (int*)(ws + 32768);     // 32 KiB
    float*  srt_sv   = (float*)(ws + 65536);   // 32 KiB
    float4* srt_box  = (float4*)(ws + 98304);  // 128 KiB
    float4* cbox     = (float4*)(ws + 229376); // 128 KiB
    int*    crank    = (int*)(ws + 360448);    // 32 KiB
    int*    meta     = (int*)(ws + 393216);    // 1 KiB (padded)
    u64*    remG     = (u64*)(ws + 394240);    // 1 KiB
    u64*    mask     = (u64*)(ws + 395264);    // V*W*8 B (realistic ~170 KiB)
    float* out = (float*)d_out;

    k_sort1<<<1, NT, 0, stream>>>(scores, pref_ex, tmp_idx);
    k_rank<<<32, 256, 0, stream>>>(scores, boxes, img, tmp_idx, pref_ex,
                                   srt_box, srt_sv);
    k_compact<<<1, NT, 0, stream>>>(srt_box, srt_sv, cbox, crank, meta);
    k_mask<<<256, 256, 0, stream>>>(cbox, meta, mask);
    k_resolve<<<1, NT, 0, stream>>>(mask, meta, remG);
    k_out<<<4, 256, 0, stream>>>(srt_box, srt_sv, crank, remG, out);
}

// Round 15
// 50.366 us; speedup vs baseline: 2.3466x; 1.1865x over previous
//
#include <hip/hip_runtime.h>

#define NPROP 8192
#define NT 1024
typedef unsigned long long u64;

__device__ __forceinline__ int bucket_of(float s) {
    int b = (int)(s * 8192.0f);   // exact: *2^13 is an exponent shift
    return b < 0 ? 0 : (b > NPROP - 1 ? NPROP - 1 : b);
}

__device__ __forceinline__ bool iou_gt_thr(float4 a, float4 b) {
    float areaA = (a.z - a.x) * (a.w - a.y);
    float areaB = (b.z - b.x) * (b.w - b.y);
    float lx = fmaxf(a.x, b.x), ly = fmaxf(a.y, b.y);
    float rx = fminf(a.z, b.z), ry = fminf(a.w, b.w);
    float w = fmaxf(rx - lx, 0.0f), h = fmaxf(ry - ly, 0.0f);
    float inter = w * h;
    float uni = areaA + areaB - inter;
    float iou = inter / fmaxf(uni, 1e-6f);
    return iou > 0.3f;
}

// K0: per-proposal validity (grid-wide, replaces single-CU compact prep)
__global__ __launch_bounds__(256)
void k_valid(const float* __restrict__ boxes, const float* __restrict__ scores,
             const float* __restrict__ img, unsigned char* __restrict__ vbyte) {
    int i = blockIdx.x * 256 + threadIdx.x;
    float4 bx = reinterpret_cast<const float4*>(boxes)[i];
    float s = scores[i];
    float ix1 = img[0], iy1 = img[1], ix2 = img[2], iy2 = img[3];
    float img_area = (ix2 - ix1) * (iy2 - iy1);
    float w = bx.z - bx.x, h = bx.w - bx.y;
    float ratio = w / (h + 1e-12f);
    bool vs = (ratio > 0.25f) && (ratio < 4.0f);
    float lx = fmaxf(ix1, bx.x), ly = fmaxf(iy1, bx.y);
    float rx = fminf(ix2, bx.z), ry = fminf(iy2, bx.w);
    float iw = fmaxf(rx - lx, 0.0f), ih = fmaxf(ry - ly, 0.0f);
    float iof = (iw * ih) / fmaxf(img_area, 1e-6f);
    vbyte[i] = (vs && (iof > 0.01f) && (s > 0.85f)) ? 1 : 0;
}

// K1: packed LDS histogram (all | valid<<16) + scan + tagged scatter + meta
__global__ __launch_bounds__(NT)
void k_sort1(const float* __restrict__ scores, const unsigned char* __restrict__ vbyte,
             unsigned* __restrict__ prefP, int* __restrict__ tmp_idx,
             int* __restrict__ meta) {
    __shared__ int hist[NPROP];   // 32 KiB: packed counts -> allocator
    __shared__ int wsum[16], wexcl[16];
    const int tid = threadIdx.x, lane = tid & 63, wave = tid >> 6;
    #pragma unroll
    for (int u = 0; u < 8; u++) hist[tid * 8 + u] = 0;
    __syncthreads();
    const float4* s4 = reinterpret_cast<const float4*>(scores);
    float4 sa = s4[tid * 2], sb = s4[tid * 2 + 1];
    float ss[8] = {sa.x, sa.y, sa.z, sa.w, sb.x, sb.y, sb.z, sb.w};
    u64 vb8 = reinterpret_cast<const u64*>(vbyte)[tid];
    int bk[8], vf[8];
    #pragma unroll
    for (int u = 0; u < 8; u++) {
        bk[u] = bucket_of(ss[u]);
        vf[u] = (int)((vb8 >> (8 * u)) & 1ull);
        atomicAdd(&hist[bk[u]], 1 + (vf[u] << 16));
    }
    __syncthreads();
    int h[8]; int tot = 0;
    #pragma unroll
    for (int u = 0; u < 8; u++) { h[u] = hist[tid * 8 + u]; tot += h[u]; }
    int incl = tot;
    #pragma unroll
    for (int off = 1; off < 64; off <<= 1) {
        int n = __shfl_up(incl, off, 64);
        if (lane >= off) incl += n;
    }
    if (lane == 63) wsum[wave] = incl;
    __syncthreads();
    if (tid == 0) {
        int acc = 0;
        #pragma unroll
        for (int w = 0; w < 16; w++) { int t = wsum[w]; wexcl[w] = acc; acc += t; }
        int Vraw = acc >> 16;                 // total valid
        int V = Vraw == 0 ? 1 : Vraw;
        meta[0] = V;
        meta[1] = (V + 63) >> 6;
        meta[2] = Vraw;
    }
    __syncthreads();
    int run = wexcl[wave] + (incl - tot);     // packed prefix
    int runA = run & 0xffff;                  // all-count prefix (allocator)
    #pragma unroll
    for (int u = 0; u < 8; u++) { prefP[tid * 8 + u] = (unsigned)run; run += h[u]; }
    __syncthreads();   // all hist reads done before overwrite as allocator
    #pragma unroll
    for (int u = 0; u < 8; u++) { hist[tid * 8 + u] = runA; runA += h[u] & 0xffff; }
    __syncthreads();
    #pragma unroll
    for (int u = 0; u < 8; u++) {
        int slot = atomicAdd(&hist[bk[u]], 1);
        tmp_idx[slot] = (tid * 8 + u) | (vf[u] << 31);   // validity-tagged index
    }
}

// K2: exact stable rank + compact position in one pass (kills k_compact)
__global__ void k_rank(const float* __restrict__ scores, const float* __restrict__ boxes,
                       const int* __restrict__ tmp_idx, const unsigned* __restrict__ prefP,
                       const int* __restrict__ meta,
                       float4* __restrict__ srt_box, float* __restrict__ srt_s,
                       int* __restrict__ crank, float4* __restrict__ cbox) {
    int p = blockIdx.x * blockDim.x + threadIdx.x;
    int ip = tmp_idx[p];
    int i = ip & 0xffff;
    bool vf = ip < 0;
    float s = scores[i];
    u64 key = ((u64)__float_as_uint(s) << 32) | (u64)(unsigned)(NPROP - 1 - i);
    int b = bucket_of(s);
    unsigned pb = prefP[b];
    int lo = (int)(pb & 0xffffu), vlo = (int)(pb >> 16);
    int hi = (b < NPROP - 1) ? (int)(prefP[b + 1] & 0xffffu) : NPROP;
    int cnt = 0, vcnt = 0;
    for (int q = lo; q < hi; q++) {
        int jp = tmp_idx[q];
        int j = jp & 0xffff;
        int vfj = (int)((unsigned)jp >> 31);
        u64 kj = ((u64)__float_as_uint(scores[j]) << 32) | (u64)(unsigned)(NPROP - 1 - j);
        int less = (kj < key) ? 1 : 0;
        cnt += less; vcnt += less & vfj;
    }
    int rank = NPROP - 1 - (lo + cnt);        // descending, stable
    float4 bx = reinterpret_cast<const float4*>(boxes)[i];
    srt_box[rank] = bx;
    srt_s[rank] = s;
    int Vraw = meta[2];
    if (vf) {
        int cpos = Vraw - 1 - (vlo + vcnt);   // compact pos among valid (descending)
        crank[rank] = cpos;
        cbox[cpos] = bx;
    } else {
        crank[rank] = -1;
    }
    if (Vraw == 0 && rank == 0) { crank[0] = 0; cbox[0] = bx; }   // fallback
}

// K3: suppression mask matrix — wave per row, lane per column
__global__ __launch_bounds__(256)
void k_mask(const float4* __restrict__ cbox, const int* __restrict__ meta,
            u64* __restrict__ mask) {
    const int V = meta[0], W = meta[1];
    const int lane = threadIdx.x & 63;
    int gw = blockIdx.x * 4 + (threadIdx.x >> 6);
    for (int r = gw; r < V; r += 1024) {
        float4 br = cbox[r];
        for (int w = (r >> 6); w < W; w++) {
            int col = w * 64 + lane;
            bool ok = (col < V) && (col > r) && iou_gt_thr(br, cbox[col]);
            u64 bal = __ballot(ok);
            if (lane == 0) mask[(u64)r * W + w] = bal;
        }
    }
}

// K4: pipelined pull-resolve: chain(b) runs concurrently with gathers for b+1
__global__ __launch_bounds__(NT)
void k_resolve(const u64* __restrict__ mask, const int* __restrict__ meta,
               u64* __restrict__ remG) {
    __shared__ u64 rem[NPROP / 64];   // 1 KiB
    __shared__ u64 diagb[2][64];      // diag words, ping-pong
    __shared__ u64 nextw[64];         // rows of block b, col-word b+1
    __shared__ u64 pullw[2];
    __shared__ int klidx[NPROP];      // kept-row indices
    __shared__ int Ksh;
    const int V = meta[0], W = meta[1];
    const int tid = threadIdx.x, lane = tid & 63, wave = tid >> 6;

    for (int w = tid; w < NPROP / 64; w += NT) {
        int b0 = w * 64; u64 m;
        if (b0 >= V) m = ~0ull;
        else if (b0 + 64 <= V) m = 0ull;
        else m = (~0ull) << (V - b0);
        rem[w] = m;
    }
    if (tid == 0) { Ksh = 0; pullw[0] = 0; pullw[1] = 0; }
    if (wave == 15) diagb[0][lane] = (lane < V) ? mask[(u64)lane * W] : 0ull;
    __syncthreads();

    for (int b = 0; b < W; b++) {
        const int rb0 = b << 6;
        const int nb = b + 1;
        const int K = Ksh;            // kept through block b-1 (stable this phase)
        u64 keptb = 0;
        // ---- phase 1: chain(b) on wave 0 || prefetch for b+1 on waves 1..15 ----
        if (wave == 0) {
            u64 d = diagb[b & 1][lane];
            int dlo = (int)(unsigned)(d & 0xffffffffull);
            int dhi = (int)(unsigned)(d >> 32);
            u64 r0 = rem[b] | pullw[b & 1];
            unsigned rl_ = (unsigned)__builtin_amdgcn_readfirstlane((int)(unsigned)(r0 & 0xffffffffull));
            unsigned rh_ = (unsigned)__builtin_amdgcn_readfirstlane((int)(unsigned)(r0 >> 32));
            u64 r = ((u64)rh_ << 32) | (u64)rl_;
            u64 avail = ~r;           // candidates (pad bits pre-removed)
            while (avail) {
                int i = (int)__builtin_ctzll(avail);          // lowest candidate -> KEPT
                unsigned xl = (unsigned)__builtin_amdgcn_readlane(dlo, i);
                unsigned xh = (unsigned)__builtin_amdgcn_readlane(dhi, i);
                u64 di = ((u64)xh << 32) | (u64)xl;
                r |= di;
                u64 x = avail & ~di;
                avail = x & (x - 1);
            }
            keptb = ~r;
            if (lane == 0) rem[b] = r;
        } else if (wave <= 13) {
            if (nb < W) {             // pull words of previously-kept rows
                u64 myor = 0;
                for (int t = (wave - 1) * 64 + lane; t < K; t += 13 * 64)
                    myor |= mask[(u64)klidx[t] * W + nb];
                #pragma unroll
                for (int off = 1; off < 64; off <<= 1)
                    myor |= __shfl_xor(myor, off, 64);
                if (lane == 0 && myor)
                    atomicOr((unsigned long long*)&pullw[nb & 1], myor);
            }
        } else if (wave == 14) {
            if (nb < W) {             // rows of block b -> their word nb
                int r_ = rb0 + lane;
                nextw[lane] = (r_ < V) ? mask[(u64)r_ * W + nb] : 0ull;
            }
        } else {                      // wave 15: diag of block nb
            if (nb < W) {
                int r_ = (nb << 6) + lane;
                diagb[nb & 1][lane] = (r_ < V) ? mask[(u64)r_ * W + nb] : 0ull;
            }
        }
        __syncthreads();
        // ---- phase 2: new-kept contribution + bookkeeping ----
        if (wave == 0) {
            if (nb < W) {
                u64 t = ((keptb >> lane) & 1ull) ? nextw[lane] : 0ull;
                #pragma unroll
                for (int off = 1; off < 64; off <<= 1)
                    t |= __shfl_xor(t, off, 64);
                if (lane == 0 && t)
                    atomicOr((unsigned long long*)&pullw[nb & 1], t);
            }
            if ((keptb >> lane) & 1ull) {
                int pos = (int)__popcll(keptb & ((1ull << lane) - 1ull));
                klidx[K + pos] = rb0 + lane;
            }
            if (lane == 0) Ksh = K + (int)__popcll(keptb);
        } else if (tid == 64) {
            pullw[b & 1] = 0;         // consumed; clean slot for block b+2
        }
        __syncthreads();
    }

    for (int w = tid; w < NPROP / 64; w += NT) remG[w] = rem[w];
}

// K5: final output [N,5]*keep + keep mask, vectorized float4 stores (4 CUs)
__global__ __launch_bounds__(256)
void k_out(const float4* __restrict__ srt_box, const float* __restrict__ srt_s,
           const int* __restrict__ crank, const u64* __restrict__ remG,
           float* __restrict__ out) {
    int tid = blockIdx.x * 256 + threadIdx.x;   // 0..1023, 8 positions each
    float ob[40]; float om[8];
    #pragma unroll
    for (int u = 0; u < 8; u++) {
        int p = tid * 8 + u;
        float4 b = srt_box[p];
        float s = srt_s[p];
        int k = crank[p];
        bool keep = (k >= 0) && !((remG[k >> 6] >> (k & 63)) & 1ull);
        float m = keep ? 1.0f : 0.0f;
        ob[u * 5 + 0] = b.x * m;
        ob[u * 5 + 1] = b.y * m;
        ob[u * 5 + 2] = b.z * m;
        ob[u * 5 + 3] = b.w * m;
        ob[u * 5 + 4] = s * m;
        om[u] = m;
    }
    float4* o4 = reinterpret_cast<float4*>(out) + tid * 10;
    #pragma unroll
    for (int q = 0; q < 10; q++)
        o4[q] = make_float4(ob[q * 4 + 0], ob[q * 4 + 1], ob[q * 4 + 2], ob[q * 4 + 3]);
    float4* m4 = reinterpret_cast<float4*>(out + NPROP * 5) + tid * 2;
    m4[0] = make_float4(om[0], om[1], om[2], om[3]);
    m4[1] = make_float4(om[4], om[5], om[6], om[7]);
}

extern "C" void kernel_launch(void* const* d_in, const int* in_sizes, int n_in,
                              void* d_out, int out_size, void* d_ws, size_t ws_size,
                              hipStream_t stream) {
    const float* boxes  = (const float*)d_in[0];
    const float* scores = (const float*)d_in[1];
    const float* img    = (const float*)d_in[2];
    char* ws = (char*)d_ws;
    unsigned* prefP  = (unsigned*)(ws + 0);            // 32 KiB
    int*    tmp_idx  = (int*)(ws + 32768);             // 32 KiB
    unsigned char* vbyte = (unsigned char*)(ws + 65536); // 8 KiB
    float*  srt_s    = (float*)(ws + 73728);           // 32 KiB
    float4* srt_box  = (float4*)(ws + 106496);         // 128 KiB
    float4* cbox     = (float4*)(ws + 237568);         // 128 KiB
    int*    crank    = (int*)(ws + 368640);            // 32 KiB
    int*    meta     = (int*)(ws + 401408);            // 1 KiB (padded)
    u64*    remG     = (u64*)(ws + 402432);            // 1 KiB
    u64*    mask     = (u64*)(ws + 403456);            // V*W*8 B (~170 KiB realistic)
    float* out = (float*)d_out;

    k_valid<<<32, 256, 0, stream>>>(boxes, scores, img, vbyte);
    k_sort1<<<1, NT, 0, stream>>>(scores, vbyte, prefP, tmp_idx, meta);
    k_rank<<<32, 256, 0, stream>>>(scores, boxes, tmp_idx, prefP, meta,
                                   srt_box, srt_s, crank, cbox);
    k_mask<<<256, 256, 0, stream>>>(cbox, meta, mask);
    k_resolve<<<1, NT, 0, stream>>>(mask, meta, remG);
    k_out<<<4, 256, 0, stream>>>(srt_box, srt_s, crank, remG, out);
}

// Round 16
// 49.062 us; speedup vs baseline: 2.4090x; 1.0266x over previous
//
#include <hip/hip_runtime.h>

#define NPROP 8192
#define NT 1024
typedef unsigned long long u64;

__device__ __forceinline__ int bucket_of(float s) {
    int b = (int)(s * 8192.0f);   // exact: *2^13 is an exponent shift
    return b < 0 ? 0 : (b > NPROP - 1 ? NPROP - 1 : b);
}

__device__ __forceinline__ bool iou_gt_thr(float4 a, float4 b) {
    float areaA = (a.z - a.x) * (a.w - a.y);
    float areaB = (b.z - b.x) * (b.w - b.y);
    float lx = fmaxf(a.x, b.x), ly = fmaxf(a.y, b.y);
    float rx = fminf(a.z, b.z), ry = fminf(a.w, b.w);
    float w = fmaxf(rx - lx, 0.0f), h = fmaxf(ry - ly, 0.0f);
    float inter = w * h;
    float uni = areaA + areaB - inter;
    float iou = inter / fmaxf(uni, 1e-6f);
    return iou > 0.3f;
}

// K0: per-proposal validity (grid-wide)
__global__ __launch_bounds__(256)
void k_valid(const float* __restrict__ boxes, const float* __restrict__ scores,
             const float* __restrict__ img, unsigned char* __restrict__ vbyte) {
    int i = blockIdx.x * 256 + threadIdx.x;
    float4 bx = reinterpret_cast<const float4*>(boxes)[i];
    float s = scores[i];
    float ix1 = img[0], iy1 = img[1], ix2 = img[2], iy2 = img[3];
    float img_area = (ix2 - ix1) * (iy2 - iy1);
    float w = bx.z - bx.x, h = bx.w - bx.y;
    float ratio = w / (h + 1e-12f);
    bool vs = (ratio > 0.25f) && (ratio < 4.0f);
    float lx = fmaxf(ix1, bx.x), ly = fmaxf(iy1, bx.y);
    float rx = fminf(ix2, bx.z), ry = fminf(iy2, bx.w);
    float iw = fmaxf(rx - lx, 0.0f), ih = fmaxf(ry - ly, 0.0f);
    float iof = (iw * ih) / fmaxf(img_area, 1e-6f);
    vbyte[i] = (vs && (iof > 0.01f) && (s > 0.85f)) ? 1 : 0;
}

// K1: packed LDS histogram (all | valid<<16) + scan + tagged scatter + meta
__global__ __launch_bounds__(NT)
void k_sort1(const float* __restrict__ scores, const unsigned char* __restrict__ vbyte,
             unsigned* __restrict__ prefP, int* __restrict__ tmp_idx,
             int* __restrict__ meta) {
    __shared__ int hist[NPROP];   // 32 KiB: packed counts -> allocator
    __shared__ int wsum[16], wexcl[16];
    const int tid = threadIdx.x, lane = tid & 63, wave = tid >> 6;
    #pragma unroll
    for (int u = 0; u < 8; u++) hist[tid * 8 + u] = 0;
    __syncthreads();
    const float4* s4 = reinterpret_cast<const float4*>(scores);
    float4 sa = s4[tid * 2], sb = s4[tid * 2 + 1];
    float ss[8] = {sa.x, sa.y, sa.z, sa.w, sb.x, sb.y, sb.z, sb.w};
    u64 vb8 = reinterpret_cast<const u64*>(vbyte)[tid];
    int bk[8], vf[8];
    #pragma unroll
    for (int u = 0; u < 8; u++) {
        bk[u] = bucket_of(ss[u]);
        vf[u] = (int)((vb8 >> (8 * u)) & 1ull);
        atomicAdd(&hist[bk[u]], 1 + (vf[u] << 16));
    }
    __syncthreads();
    int h[8]; int tot = 0;
    #pragma unroll
    for (int u = 0; u < 8; u++) { h[u] = hist[tid * 8 + u]; tot += h[u]; }
    int incl = tot;
    #pragma unroll
    for (int off = 1; off < 64; off <<= 1) {
        int n = __shfl_up(incl, off, 64);
        if (lane >= off) incl += n;
    }
    if (lane == 63) wsum[wave] = incl;
    __syncthreads();
    if (tid == 0) {
        int acc = 0;
        #pragma unroll
        for (int w = 0; w < 16; w++) { int t = wsum[w]; wexcl[w] = acc; acc += t; }
        int Vraw = acc >> 16;                 // total valid
        int V = Vraw == 0 ? 1 : Vraw;
        meta[0] = V;
        meta[1] = (V + 63) >> 6;
        meta[2] = Vraw;
    }
    __syncthreads();
    int run = wexcl[wave] + (incl - tot);     // packed prefix
    int runA = run & 0xffff;                  // all-count prefix (allocator)
    #pragma unroll
    for (int u = 0; u < 8; u++) { prefP[tid * 8 + u] = (unsigned)run; run += h[u]; }
    __syncthreads();   // all hist reads done before overwrite as allocator
    #pragma unroll
    for (int u = 0; u < 8; u++) { hist[tid * 8 + u] = runA; runA += h[u] & 0xffff; }
    __syncthreads();
    #pragma unroll
    for (int u = 0; u < 8; u++) {
        int slot = atomicAdd(&hist[bk[u]], 1);
        tmp_idx[slot] = (tid * 8 + u) | (vf[u] << 31);   // validity-tagged index
    }
}

// K2: exact stable rank + compact position in one pass
__global__ void k_rank(const float* __restrict__ scores, const float* __restrict__ boxes,
                       const int* __restrict__ tmp_idx, const unsigned* __restrict__ prefP,
                       const int* __restrict__ meta,
                       float4* __restrict__ srt_box, float* __restrict__ srt_s,
                       int* __restrict__ crank, float4* __restrict__ cbox) {
    int p = blockIdx.x * blockDim.x + threadIdx.x;
    int ip = tmp_idx[p];
    int i = ip & 0xffff;
    bool vf = ip < 0;
    float s = scores[i];
    u64 key = ((u64)__float_as_uint(s) << 32) | (u64)(unsigned)(NPROP - 1 - i);
    int b = bucket_of(s);
    unsigned pb = prefP[b];
    int lo = (int)(pb & 0xffffu), vlo = (int)(pb >> 16);
    int hi = (b < NPROP - 1) ? (int)(prefP[b + 1] & 0xffffu) : NPROP;
    int cnt = 0, vcnt = 0;
    for (int q = lo; q < hi; q++) {
        int jp = tmp_idx[q];
        int j = jp & 0xffff;
        int vfj = (int)((unsigned)jp >> 31);
        u64 kj = ((u64)__float_as_uint(scores[j]) << 32) | (u64)(unsigned)(NPROP - 1 - j);
        int less = (kj < key) ? 1 : 0;
        cnt += less; vcnt += less & vfj;
    }
    int rank = NPROP - 1 - (lo + cnt);        // descending, stable
    float4 bx = reinterpret_cast<const float4*>(boxes)[i];
    srt_box[rank] = bx;
    srt_s[rank] = s;
    int Vraw = meta[2];
    if (vf) {
        int cpos = Vraw - 1 - (vlo + vcnt);   // compact pos among valid (descending)
        crank[rank] = cpos;
        cbox[cpos] = bx;
    } else {
        crank[rank] = -1;
    }
    if (Vraw == 0 && rank == 0) { crank[0] = 0; cbox[0] = bx; }   // fallback
}

// K3: suppression mask matrix — COLUMN-MAJOR: mask[w*VP + r]
__global__ __launch_bounds__(256)
void k_mask(const float4* __restrict__ cbox, const int* __restrict__ meta,
            u64* __restrict__ mask) {
    const int V = meta[0], W = meta[1];
    const int VP = W << 6;
    const int lane = threadIdx.x & 63;
    int gw = blockIdx.x * 4 + (threadIdx.x >> 6);
    for (int r = gw; r < V; r += 1024) {
        float4 br = cbox[r];
        for (int w = (r >> 6); w < W; w++) {
            int col = w * 64 + lane;
            bool ok = (col < V) && (col > r) && iou_gt_thr(br, cbox[col]);
            u64 bal = __ballot(ok);
            if (lane == 0) mask[(u64)w * VP + r] = bal;
        }
    }
}

// K4: pipelined pull-resolve (column-major mask: coalesced diag/nextw, dense pulls)
__global__ __launch_bounds__(NT)
void k_resolve(const u64* __restrict__ mask, const int* __restrict__ meta,
               u64* __restrict__ remG) {
    __shared__ u64 rem[NPROP / 64];   // 1 KiB
    __shared__ u64 diagb[2][64];      // diag words, ping-pong
    __shared__ u64 nextw[64];         // rows of block b, col-word b+1
    __shared__ u64 pullw[2];
    __shared__ int klidx[NPROP];      // kept-row indices
    __shared__ int Ksh;
    const int V = meta[0], W = meta[1];
    const int VP = W << 6;
    const int tid = threadIdx.x, lane = tid & 63, wave = tid >> 6;

    for (int w = tid; w < NPROP / 64; w += NT) {
        int b0 = w * 64; u64 m;
        if (b0 >= V) m = ~0ull;
        else if (b0 + 64 <= V) m = 0ull;
        else m = (~0ull) << (V - b0);
        rem[w] = m;
    }
    if (tid == 0) { Ksh = 0; pullw[0] = 0; pullw[1] = 0; }
    if (wave == 15) diagb[0][lane] = (lane < V) ? mask[lane] : 0ull;
    __syncthreads();

    for (int b = 0; b < W; b++) {
        const int rb0 = b << 6;
        const int nb = b + 1;
        const int K = Ksh;            // kept through block b-1 (stable this phase)
        u64 keptb = 0;
        // ---- phase 1: chain(b) on wave 0 || prefetch for b+1 on waves 1..15 ----
        if (wave == 0) {
            u64 d = diagb[b & 1][lane];
            int dlo = (int)(unsigned)(d & 0xffffffffull);
            int dhi = (int)(unsigned)(d >> 32);
            u64 r0 = rem[b] | pullw[b & 1];
            unsigned rl_ = (unsigned)__builtin_amdgcn_readfirstlane((int)(unsigned)(r0 & 0xffffffffull));
            unsigned rh_ = (unsigned)__builtin_amdgcn_readfirstlane((int)(unsigned)(r0 >> 32));
            u64 r = ((u64)rh_ << 32) | (u64)rl_;
            u64 avail = ~r;           // candidates (pad bits pre-removed)
            while (avail) {
                int i = (int)__builtin_ctzll(avail);          // lowest candidate -> KEPT
                unsigned xl = (unsigned)__builtin_amdgcn_readlane(dlo, i);
                unsigned xh = (unsigned)__builtin_amdgcn_readlane(dhi, i);
                u64 di = ((u64)xh << 32) | (u64)xl;
                r |= di;
                u64 x = avail & ~di;
                avail = x & (x - 1);
            }
            keptb = ~r;
            if (lane == 0) rem[b] = r;
        } else if (wave <= 13) {
            if (nb < W) {             // pull words of previously-kept rows
                u64 myor = 0;
                for (int t = (wave - 1) * 64 + lane; t < K; t += 13 * 64)
                    myor |= mask[(u64)nb * VP + klidx[t]];
                #pragma unroll
                for (int off = 1; off < 64; off <<= 1)
                    myor |= __shfl_xor(myor, off, 64);
                if (lane == 0 && myor)
                    atomicOr((unsigned long long*)&pullw[nb & 1], myor);
            }
        } else if (wave == 14) {
            if (nb < W) {             // rows of block b -> their word nb (coalesced)
                int r_ = rb0 + lane;
                nextw[lane] = (r_ < V) ? mask[(u64)nb * VP + r_] : 0ull;
            }
        } else {                      // wave 15: diag of block nb (coalesced)
            if (nb < W) {
                int r_ = (nb << 6) + lane;
                diagb[nb & 1][lane] = (r_ < V) ? mask[(u64)nb * VP + r_] : 0ull;
            }
        }
        __syncthreads();
        // ---- phase 2: new-kept contribution + bookkeeping ----
        if (wave == 0) {
            if (nb < W) {
                u64 t = ((keptb >> lane) & 1ull) ? nextw[lane] : 0ull;
                #pragma unroll
                for (int off = 1; off < 64; off <<= 1)
                    t |= __shfl_xor(t, off, 64);
                if (lane == 0 && t)
                    atomicOr((unsigned long long*)&pullw[nb & 1], t);
            }
            if ((keptb >> lane) & 1ull) {
                int pos = (int)__popcll(keptb & ((1ull << lane) - 1ull));
                klidx[K + pos] = rb0 + lane;
            }
            if (lane == 0) Ksh = K + (int)__popcll(keptb);
        } else if (tid == 64) {
            pullw[b & 1] = 0;         // consumed; clean slot for block b+2
        }
        __syncthreads();
    }

    for (int w = tid; w < NPROP / 64; w += NT) remG[w] = rem[w];
}

// K5: final output [N,5]*keep + keep mask (8 blocks, 4 positions/thread)
__global__ __launch_bounds__(256)
void k_out(const float4* __restrict__ srt_box, const float* __restrict__ srt_s,
           const int* __restrict__ crank, const u64* __restrict__ remG,
           float* __restrict__ out) {
    int tid = blockIdx.x * 256 + threadIdx.x;   // 0..2047, 4 positions each
    float ob[20]; float om[4];
    #pragma unroll
    for (int u = 0; u < 4; u++) {
        int p = tid * 4 + u;
        float4 b = srt_box[p];
        float s = srt_s[p];
        int k = crank[p];
        bool keep = (k >= 0) && !((remG[k >> 6] >> (k & 63)) & 1ull);
        float m = keep ? 1.0f : 0.0f;
        ob[u * 5 + 0] = b.x * m;
        ob[u * 5 + 1] = b.y * m;
        ob[u * 5 + 2] = b.z * m;
        ob[u * 5 + 3] = b.w * m;
        ob[u * 5 + 4] = s * m;
        om[u] = m;
    }
    float4* o4 = reinterpret_cast<float4*>(out) + tid * 5;
    #pragma unroll
    for (int q = 0; q < 5; q++)
        o4[q] = make_float4(ob[q * 4 + 0], ob[q * 4 + 1], ob[q * 4 + 2], ob[q * 4 + 3]);
    reinterpret_cast<float4*>(out + NPROP * 5)[tid] =
        make_float4(om[0], om[1], om[2], om[3]);
}

extern "C" void kernel_launch(void* const* d_in, const int* in_sizes, int n_in,
                              void* d_out, int out_size, void* d_ws, size_t ws_size,
                              hipStream_t stream) {
    const float* boxes  = (const float*)d_in[0];
    const float* scores = (const float*)d_in[1];
    const float* img    = (const float*)d_in[2];
    char* ws = (char*)d_ws;
    unsigned* prefP  = (unsigned*)(ws + 0);            // 32 KiB
    int*    tmp_idx  = (int*)(ws + 32768);             // 32 KiB
    unsigned char* vbyte = (unsigned char*)(ws + 65536); // 8 KiB
    float*  srt_s    = (float*)(ws + 73728);           // 32 KiB
    float4* srt_box  = (float4*)(ws + 106496);         // 128 KiB
    float4* cbox     = (float4*)(ws + 237568);         // 128 KiB
    int*    crank    = (int*)(ws + 368640);            // 32 KiB
    int*    meta     = (int*)(ws + 401408);            // 1 KiB (padded)
    u64*    remG     = (u64*)(ws + 402432);            // 1 KiB
    u64*    mask     = (u64*)(ws + 403456);            // W*VP*8 B (~170 KiB realistic)
    float* out = (float*)d_out;

    k_valid<<<32, 256, 0, stream>>>(boxes, scores, img, vbyte);
    k_sort1<<<1, NT, 0, stream>>>(scores, vbyte, prefP, tmp_idx, meta);
    k_rank<<<32, 256, 0, stream>>>(scores, boxes, tmp_idx, prefP, meta,
                                   srt_box, srt_s, crank, cbox);
    k_mask<<<256, 256, 0, stream>>>(cbox, meta, mask);
    k_resolve<<<1, NT, 0, stream>>>(mask, meta, remG);
    k_out<<<8, 256, 0, stream>>>(srt_box, srt_s, crank, remG, out);
}